// Round 3
// baseline (44.580 us; speedup 1.0000x reference)
//
#include <hip/hip_runtime.h>
#include <hip/hip_bf16.h>

#define S_IMG    128
#define KTOP     16
#define NPTS_MAX 2048
#define RAD2     (0.02f*0.02f)
#define INV_R2   (1.0f/RAD2)
#define RADF     0.02f
#define ZNEARF   1.0f
#define FOCALF   1.7320508075688772f   // 1/tan(30 deg)
#define TH       8                     // tile height (pixel rows)
#define TW       16                    // tile width  (pixel cols)
#define TPB      (TH*TW)               // 128 threads, 1 px/thread
#define KSENT    0xFFFFFFFFu

__global__ __launch_bounds__(TPB) void render_tile(
    const float* __restrict__ points,
    const float* __restrict__ eye,
    const float* __restrict__ colors,
    float* __restrict__ out,
    int N)
{
    __shared__ float    s_cxy[NPTS_MAX * 2];  // candidate (x_ndc, y_ndc)
    __shared__ unsigned s_ck [NPTS_MAX];      // candidate key: (z bits & ~2047) | idx
    __shared__ int      s_cnt;

    const int tid = threadIdx.x;
    const int blk = blockIdx.x;
    const int b   = blk >> 7;                 // 128 tiles per image
    const int t   = blk & 127;
    const int tr  = t >> 3;                   // tile row (0..15)
    const int tc  = t & 7;                    // tile col (0..7)
    const int r0  = tr * TH, c0 = tc * TW;

    // ---- camera basis (PyTorch3D look_at: at=origin, up=+y; R cols = x,y,z) ----
    const float ex = eye[b*3+0], ey = eye[b*3+1], ez = eye[b*3+2];
    const float zinv = 1.0f / sqrtf(ex*ex + ey*ey + ez*ez);
    const float zax = -ex*zinv, zay = -ey*zinv, zaz = -ez*zinv;
    const float xinv = 1.0f / sqrtf(zaz*zaz + zax*zax);
    const float xax = zaz*xinv, xaz = -zax*xinv;       // x-axis y-component == 0
    const float yax = zay*xaz;
    const float yay = zaz*xax - zax*xaz;
    const float yaz = -zay*xax;

    // ---- tile bbox in NDC (pixel centers span +/- (T-1)/S around center) ----
    const float cx = 1.0f - (float)(2*c0 + TW) / S_IMG;
    const float cy = 1.0f - (float)(2*r0 + TH) / S_IMG;
    const float hx = (float)(TW - 1) / S_IMG + RADF + 1e-6f;
    const float hy = (float)(TH - 1) / S_IMG + RADF + 1e-6f;

    if (tid == 0) s_cnt = 0;
    __syncthreads();

    // ---- project + cull into compact candidate list ----
    const float* pts = points + b*N*3;
    for (int j = tid; j < N; j += TPB) {
        float wx = pts[3*j+0] - ex;
        float wy = pts[3*j+1] - ey;
        float wz = pts[3*j+2] - ez;
        float cz = wx*zax + wy*zay + wz*zaz;
        if (cz > ZNEARF) {
            float cxv = wx*xax + wz*xaz;
            float cyv = wx*yax + wy*yay + wz*yaz;
            float inv = FOCALF / cz;
            float xn = cxv*inv, yn = cyv*inv;
            if (fabsf(xn - cx) <= hx && fabsf(yn - cy) <= hy) {
                int slot = atomicAdd(&s_cnt, 1);
                s_cxy[2*slot+0] = xn;
                s_cxy[2*slot+1] = yn;
                s_ck[slot] = (__float_as_uint(cz) & ~2047u) | (unsigned)j;
            }
        }
    }
    __syncthreads();
    const int M = s_cnt;

    // ---- per-pixel scan of candidates: top-16 by key (z asc, idx tie-break) ----
    const int row = r0 + (tid >> 4);
    const int col = c0 + (tid & 15);
    const float pxc = 1.0f - (2.0f*col + 1.0f) / S_IMG;
    const float pyc = 1.0f - (2.0f*row + 1.0f) / S_IMG;

    unsigned kb[KTOP];   // sort keys (positive-float bits -> uint order == z order)
    float    db[KTOP];   // d2 payload (full precision)
    #pragma unroll
    for (int q = 0; q < KTOP; ++q) { kb[q] = KSENT; db[q] = 0.0f; }

    auto insert = [&](unsigned key, float d2) {
        if (key < kb[KTOP-1]) {
            #pragma unroll
            for (int q = KTOP-1; q >= 1; --q) {
                bool lt  = key < kb[q];
                bool ltp = key < kb[q-1];
                unsigned kq = ltp ? kb[q-1] : key;
                float    dq = ltp ? db[q-1] : d2;
                kb[q] = lt ? kq : kb[q];
                db[q] = lt ? dq : db[q];
            }
            if (key < kb[0]) { kb[0] = key; db[0] = d2; }
        }
    };

    const float2* cxy2 = reinterpret_cast<const float2*>(s_cxy);
    for (int i = 0; i < M; ++i) {
        float2 v = cxy2[i];                    // uniform addr -> LDS broadcast
        float dx = pxc - v.x, dy = pyc - v.y;
        float d2 = dx*dx + dy*dy;
        if (d2 < RAD2) insert(s_ck[i], d2);
    }

    // ---- front-to-back alpha compositing ----
    const float* cols = colors + b*N*3;
    float T = 1.0f, r = 0.0f, g = 0.0f, bl = 0.0f;
    #pragma unroll
    for (int q = 0; q < KTOP; ++q) {
        if (kb[q] != KSENT) {
            int   j  = (int)(kb[q] & 2047u);
            float alpha = 1.0f - db[q] * INV_R2;
            float w = alpha * T;
            r  += w * cols[3*j+0];
            g  += w * cols[3*j+1];
            bl += w * cols[3*j+2];
            T *= 1.0f - alpha;
        }
    }

    const int gpix = b * (S_IMG*S_IMG) + row * S_IMG + col;
    float* o = out + (size_t)gpix * 3;
    o[0] = r; o[1] = g; o[2] = bl;
}

extern "C" void kernel_launch(void* const* d_in, const int* in_sizes, int n_in,
                              void* d_out, int out_size, void* d_ws, size_t ws_size,
                              hipStream_t stream)
{
    const float* points = (const float*)d_in[0];
    const float* eye    = (const float*)d_in[1];
    const float* colors = (const float*)d_in[2];
    float* out = (float*)d_out;

    const int B = in_sizes[1] / 3;              // eye is [B,3]
    const int N = in_sizes[0] / (3 * B);        // points is [B,N,3] (N <= NPTS_MAX)
    const int nblk = B * (S_IMG/TH) * (S_IMG/TW);

    render_tile<<<nblk, TPB, 0, stream>>>(points, eye, colors, out, N);
}

// Round 4
// 27.479 us; speedup vs baseline: 1.6223x; 1.6223x over previous
//
#include <hip/hip_runtime.h>
#include <hip/hip_bf16.h>

#define S_IMG    128
#define KTOP     16
#define RAD2     (0.02f*0.02f)
#define INV_R2   (1.0f/RAD2)
#define RADF     0.02f
#define ZNEARF   1.0f
#define FOCALF   1.7320508075688772f   // 1/tan(30 deg)
#define TH       8                     // tile height (pixel rows)
#define TW       16                    // tile width  (pixel cols)
#define TPB      (TH*TW)               // 128 threads, 1 px/thread
#define CAP      512                   // max candidates per tile (est. worst ~150)
#define KSENT    0xFFFFFFFFu

__global__ __launch_bounds__(TPB) void render_tile(
    const float* __restrict__ points,
    const float* __restrict__ eye,
    const float* __restrict__ colors,
    float* __restrict__ out,
    int N)
{
    __shared__ float4 s_cand[CAP];   // unsorted: {x_ndc, y_ndc, key_bits, -}
    __shared__ float2 s_sxy [CAP];   // z-sorted: (x_ndc, y_ndc)
    __shared__ float4 s_scol[CAP];   // z-sorted: (r, g, b, -)
    __shared__ int    s_cnt;

    const int tid = threadIdx.x;
    const int blk = blockIdx.x;
    const int b   = blk >> 7;                 // 128 tiles per image
    const int t   = blk & 127;
    const int tr  = t >> 3;                   // tile row (0..15)
    const int tc  = t & 7;                    // tile col (0..7)
    const int r0  = tr * TH, c0 = tc * TW;

    // ---- camera basis (PyTorch3D look_at: at=origin, up=+y; R cols = x,y,z) ----
    const float ex = eye[b*3+0], ey = eye[b*3+1], ez = eye[b*3+2];
    const float zinv = 1.0f / sqrtf(ex*ex + ey*ey + ez*ez);
    const float zax = -ex*zinv, zay = -ey*zinv, zaz = -ez*zinv;
    const float xinv = 1.0f / sqrtf(zaz*zaz + zax*zax);
    const float xax = zaz*xinv, xaz = -zax*xinv;       // x-axis y-component == 0
    const float yax = zay*xaz;
    const float yay = zaz*xax - zax*xaz;
    const float yaz = -zay*xax;

    // ---- tile bbox in NDC (pixel centers) + radius pad ----
    const float cx = 1.0f - (float)(2*c0 + TW) / S_IMG;
    const float cy = 1.0f - (float)(2*r0 + TH) / S_IMG;
    const float hx = (float)(TW - 1) / S_IMG + RADF + 1e-6f;
    const float hy = (float)(TH - 1) / S_IMG + RADF + 1e-6f;

    if (tid == 0) s_cnt = 0;
    __syncthreads();

    // ---- phase 1: project + tile-cull -> compact unordered candidate list ----
    const float* pts = points + b*N*3;
    #pragma unroll 4
    for (int j = tid; j < N; j += TPB) {
        float wx = pts[3*j+0] - ex;
        float wy = pts[3*j+1] - ey;
        float wz = pts[3*j+2] - ez;
        float cz = wx*zax + wy*zay + wz*zaz;
        if (cz > ZNEARF) {
            float cxv = wx*xax + wz*xaz;
            float cyv = wx*yax + wy*yay + wz*yaz;
            float inv = FOCALF / cz;
            float xn = cxv*inv, yn = cyv*inv;
            if (fabsf(xn - cx) <= hx && fabsf(yn - cy) <= hy) {
                int slot = atomicAdd(&s_cnt, 1);
                if (slot < CAP) {
                    unsigned key = (__float_as_uint(cz) & ~2047u) | (unsigned)j;
                    s_cand[slot] = make_float4(xn, yn, __uint_as_float(key), 0.0f);
                }
            }
        }
    }
    __syncthreads();
    int M = s_cnt; if (M > CAP) M = CAP;

    // ---- phase 2: rank-sort by key (unique: z-bits|idx) + gather colors ----
    const float* cols = colors + b*N*3;
    for (int o = tid; o < M; o += TPB) {
        float4 c = s_cand[o];
        unsigned mk = __float_as_uint(c.z);
        int rank = 0;
        for (int j2 = 0; j2 < M; ++j2)                 // broadcast reads (lockstep)
            rank += (__float_as_uint(s_cand[j2].z) < mk) ? 1 : 0;
        int pi = (int)(mk & 2047u);
        s_sxy [rank] = make_float2(c.x, c.y);
        s_scol[rank] = make_float4(cols[3*pi+0], cols[3*pi+1], cols[3*pi+2], 0.0f);
    }
    __syncthreads();

    // ---- phase 3: per-pixel scan of z-sorted list, composite on the fly ----
    const int row = r0 + (tid >> 4);
    const int col = c0 + (tid & 15);
    const float pxc = 1.0f - (2.0f*col + 1.0f) / S_IMG;
    const float pyc = 1.0f - (2.0f*row + 1.0f) / S_IMG;

    float T = 1.0f, r = 0.0f, g = 0.0f, bl = 0.0f;
    int hits = 0;
    for (int i = 0; i < M; ++i) {
        float2 xy = s_sxy[i];                          // LDS broadcast
        float dx = pxc - xy.x, dy = pyc - xy.y;
        float d2 = dx*dx + dy*dy;
        bool hit = (d2 < RAD2) && (hits < KTOP);
        if (__any(hit)) {                              // skip color read if no lane hits
            float4 cc = s_scol[i];
            float alpha = hit ? (1.0f - d2 * INV_R2) : 0.0f;
            hits += hit ? 1 : 0;
            float w = alpha * T;
            r  += w * cc.x;
            g  += w * cc.y;
            bl += w * cc.z;
            T  -= T * alpha;                           // T *= (1 - alpha)
        }
    }

    const int gpix = b * (S_IMG*S_IMG) + row * S_IMG + col;
    float* o = out + (size_t)gpix * 3;
    o[0] = r; o[1] = g; o[2] = bl;
}

extern "C" void kernel_launch(void* const* d_in, const int* in_sizes, int n_in,
                              void* d_out, int out_size, void* d_ws, size_t ws_size,
                              hipStream_t stream)
{
    const float* points = (const float*)d_in[0];
    const float* eye    = (const float*)d_in[1];
    const float* colors = (const float*)d_in[2];
    float* out = (float*)d_out;

    const int B = in_sizes[1] / 3;              // eye is [B,3]
    const int N = in_sizes[0] / (3 * B);        // points is [B,N,3]
    const int nblk = B * (S_IMG/TH) * (S_IMG/TW);

    render_tile<<<nblk, TPB, 0, stream>>>(points, eye, colors, out, N);
}

// Round 5
// 21.097 us; speedup vs baseline: 2.1131x; 1.3025x over previous
//
#include <hip/hip_runtime.h>
#include <hip/hip_bf16.h>

#define S_IMG    128
#define KTOP     16
#define RAD2     (0.02f*0.02f)
#define INV_R2   (1.0f/RAD2)
#define RADF     0.02f
#define ZNEARF   1.0f
#define FOCALF   1.7320508075688772f   // 1/tan(30 deg)
#define TH       8                     // tile height (pixel rows)
#define TW       16                    // tile width  (pixel cols)
#define TPB      (TH*TW)               // 128 threads, 1 px/thread
#define CAP      512                   // max candidates per tile (worst ~200 est.)

__global__ __launch_bounds__(TPB) void render_tile(
    const float* __restrict__ points,
    const float* __restrict__ eye,
    const float* __restrict__ colors,
    float* __restrict__ out,
    int N)
{
    __shared__ float                 s_cx [CAP];      // unsorted candidate x_ndc
    __shared__ float                 s_cy [CAP];      // unsorted candidate y_ndc
    __shared__ __align__(16) unsigned s_key[CAP + 8]; // (z bits & ~2047) | idx, + pad
    __shared__ __align__(16) float2  s_sxy [CAP + 4]; // z-sorted (x,y), + pad
    __shared__ __align__(16) float4  s_scol[CAP + 4]; // z-sorted (r,g,b,-), + pad
    __shared__ int s_cnt;

    const int tid = threadIdx.x;
    const int blk = blockIdx.x;
    const int b   = blk >> 7;                 // 128 tiles per image
    const int t   = blk & 127;
    const int tr  = t >> 3;                   // tile row (0..15)
    const int tc  = t & 7;                    // tile col (0..7)
    const int r0  = tr * TH, c0 = tc * TW;

    // ---- camera basis (PyTorch3D look_at: at=origin, up=+y; R cols = x,y,z) ----
    const float ex = eye[b*3+0], ey = eye[b*3+1], ez = eye[b*3+2];
    const float zinv = 1.0f / sqrtf(ex*ex + ey*ey + ez*ez);
    const float zax = -ex*zinv, zay = -ey*zinv, zaz = -ez*zinv;
    const float xinv = 1.0f / sqrtf(zaz*zaz + zax*zax);
    const float xax = zaz*xinv, xaz = -zax*xinv;       // x-axis y-component == 0
    const float yax = zay*xaz;
    const float yay = zaz*xax - zax*xaz;
    const float yaz = -zay*xax;

    // ---- tile bbox in NDC (pixel centers) + radius pad ----
    const float cx = 1.0f - (float)(2*c0 + TW) / S_IMG;
    const float cy = 1.0f - (float)(2*r0 + TH) / S_IMG;
    const float hx = (float)(TW - 1) / S_IMG + RADF + 1e-6f;
    const float hy = (float)(TH - 1) / S_IMG + RADF + 1e-6f;

    if (tid == 0) s_cnt = 0;
    __syncthreads();

    // ---- phase 1: project + tile-cull -> compact unordered candidate list ----
    const float* pts = points + b*N*3;
    #pragma unroll 4
    for (int j = tid; j < N; j += TPB) {
        float wx = pts[3*j+0] - ex;
        float wy = pts[3*j+1] - ey;
        float wz = pts[3*j+2] - ez;
        float cz = wx*zax + wy*zay + wz*zaz;
        if (cz > ZNEARF) {
            float cxv = wx*xax + wz*xaz;
            float cyv = wx*yax + wy*yay + wz*yaz;
            float inv = FOCALF / cz;
            float xn = cxv*inv, yn = cyv*inv;
            if (fabsf(xn - cx) <= hx && fabsf(yn - cy) <= hy) {
                int slot = atomicAdd(&s_cnt, 1);
                if (slot < CAP) {
                    s_cx [slot] = xn;
                    s_cy [slot] = yn;
                    s_key[slot] = (__float_as_uint(cz) & ~2047u) | (unsigned)j;
                }
            }
        }
    }
    __syncthreads();
    int M = s_cnt; if (M > CAP) M = CAP;

    // ---- pad so phase 2/3 can read in vector batches past M ----
    if (tid < 8) s_key[M + tid] = 0xFFFFFFFFu;          // never < any real key
    if (tid < 4) {
        s_sxy [M + tid] = make_float2(1.0e9f, 1.0e9f);  // never hits
        s_scol[M + tid] = make_float4(0.f, 0.f, 0.f, 0.f); // avoid NaN * 0
    }
    __syncthreads();

    // ---- phase 2: rank-sort by key (unique) + gather colors into sorted slots ----
    const float* cols = colors + b*N*3;
    const uint4* k4 = reinterpret_cast<const uint4*>(s_key);
    const int nb = (M + 7) >> 3;                        // 8 keys per iter
    for (int o = tid; o < M; o += TPB) {
        unsigned mk = s_key[o];
        int rank = 0;
        for (int q = 0; q < nb; ++q) {                  // 2x b128 broadcast reads
            uint4 a  = k4[2*q];
            uint4 bb = k4[2*q+1];
            rank += (int)(a.x  < mk) + (int)(a.y  < mk) + (int)(a.z  < mk) + (int)(a.w  < mk)
                  + (int)(bb.x < mk) + (int)(bb.y < mk) + (int)(bb.z < mk) + (int)(bb.w < mk);
        }
        int pi = (int)(mk & 2047u);
        s_sxy [rank] = make_float2(s_cx[o], s_cy[o]);
        s_scol[rank] = make_float4(cols[3*pi+0], cols[3*pi+1], cols[3*pi+2], 0.0f);
    }
    __syncthreads();

    // ---- phase 3: scan z-sorted list, composite on the fly (4 cands/iter) ----
    const int row = r0 + (tid >> 4);
    const int col = c0 + (tid & 15);
    const float pxc = 1.0f - (2.0f*col + 1.0f) / S_IMG;
    const float pyc = 1.0f - (2.0f*row + 1.0f) / S_IMG;

    const float4* xy4 = reinterpret_cast<const float4*>(s_sxy);
    float T = 1.0f, r = 0.0f, g = 0.0f, bl = 0.0f;
    int hits = 0;
    for (int i = 0; i < M; i += 4) {
        float4 u  = xy4[(i >> 1) + 0];                  // pts i, i+1
        float4 v  = xy4[(i >> 1) + 1];                  // pts i+2, i+3
        float4 c0v = s_scol[i + 0];
        float4 c1v = s_scol[i + 1];
        float4 c2v = s_scol[i + 2];
        float4 c3v = s_scol[i + 3];

        float dx, dy, d2, a, w;
        bool  h;

        dx = pxc - u.x; dy = pyc - u.y; d2 = dx*dx + dy*dy;
        h  = (d2 < RAD2) && (hits < KTOP); hits += h ? 1 : 0;
        a  = h ? 1.0f - d2 * INV_R2 : 0.0f;
        w  = a * T; r += w*c0v.x; g += w*c0v.y; bl += w*c0v.z; T -= T*a;

        dx = pxc - u.z; dy = pyc - u.w; d2 = dx*dx + dy*dy;
        h  = (d2 < RAD2) && (hits < KTOP); hits += h ? 1 : 0;
        a  = h ? 1.0f - d2 * INV_R2 : 0.0f;
        w  = a * T; r += w*c1v.x; g += w*c1v.y; bl += w*c1v.z; T -= T*a;

        dx = pxc - v.x; dy = pyc - v.y; d2 = dx*dx + dy*dy;
        h  = (d2 < RAD2) && (hits < KTOP); hits += h ? 1 : 0;
        a  = h ? 1.0f - d2 * INV_R2 : 0.0f;
        w  = a * T; r += w*c2v.x; g += w*c2v.y; bl += w*c2v.z; T -= T*a;

        dx = pxc - v.z; dy = pyc - v.w; d2 = dx*dx + dy*dy;
        h  = (d2 < RAD2) && (hits < KTOP); hits += h ? 1 : 0;
        a  = h ? 1.0f - d2 * INV_R2 : 0.0f;
        w  = a * T; r += w*c3v.x; g += w*c3v.y; bl += w*c3v.z; T -= T*a;
    }

    const int gpix = b * (S_IMG*S_IMG) + row * S_IMG + col;
    float* o = out + (size_t)gpix * 3;
    o[0] = r; o[1] = g; o[2] = bl;
}

extern "C" void kernel_launch(void* const* d_in, const int* in_sizes, int n_in,
                              void* d_out, int out_size, void* d_ws, size_t ws_size,
                              hipStream_t stream)
{
    const float* points = (const float*)d_in[0];
    const float* eye    = (const float*)d_in[1];
    const float* colors = (const float*)d_in[2];
    float* out = (float*)d_out;

    const int B = in_sizes[1] / 3;              // eye is [B,3]
    const int N = in_sizes[0] / (3 * B);        // points is [B,N,3]
    const int nblk = B * (S_IMG/TH) * (S_IMG/TW);

    render_tile<<<nblk, TPB, 0, stream>>>(points, eye, colors, out, N);
}